// Round 5
// baseline (706.208 us; speedup 1.0000x reference)
//
#include <hip/hip_runtime.h>
#include <cmath>

#define BATCH 8
#define CHN 256
#define HH 128
#define WW 128
#define HWSZ (HH*WW)
#define NCLS 81
#define NFG 80
#define KTOP 100
#define EPSV 1e-6f

typedef __attribute__((ext_vector_type(8))) short short8;
typedef __attribute__((ext_vector_type(4))) float f32x4;
typedef __attribute__((ext_vector_type(16))) float f32x16;

__device__ __forceinline__ ushort f2bf(float f) {
    unsigned u = __float_as_uint(f);
    return (ushort)((u + 0x7FFFu + ((u >> 16) & 1u)) >> 16);
}
__device__ __forceinline__ float bf2f(ushort h) {
    return __uint_as_float(((unsigned)h) << 16);
}

// async global->LDS, 16B per lane; LDS dest is wave-uniform base + lane*16
__device__ __forceinline__ void gl16(const void* g, void* l) {
    __builtin_amdgcn_global_load_lds(
        (const __attribute__((address_space(1))) void*)g,
        (__attribute__((address_space(3))) void*)l, 16, 0, 0);
}

// ===========================================================================
// prep_x: x NCHW fp32 -> xh/xl NHWC bf16 (hi + residual-lo). LDS transpose.
// Tile layout: [px][chunk c8][8] with 10-float chunk stride, 321-float row
// stride -> both write (px fast) and read (c8 fast) phases are <=2-way (free).
// ===========================================================================
__global__ __launch_bounds__(256) void prep_x(
    const float* __restrict__ x, ushort* __restrict__ xh, ushort* __restrict__ xl)
{
    __shared__ float tile[32 * 321];       // 41088 B
    const int blk = blockIdx.x;            // 4096 = 8*128*4
    const int q4 = blk & 3, h = (blk >> 2) & 127, b = blk >> 9;
    const int w0 = q4 << 5;
    const int t = threadIdx.x;
    const int px1 = t & 31, cq = t >> 5;

    const float* xb = x + ((size_t)b * CHN) * HWSZ + h * WW + w0;
#pragma unroll 4
    for (int i = 0; i < 32; ++i) {
        // c = i*8 + cq  -> chunk i, lane offset cq
        tile[px1 * 321 + i * 10 + cq] = xb[(size_t)(i * 8 + cq) * HWSZ + px1];
    }
    __syncthreads();
    for (int i = 0; i < 4; ++i) {
        int u = i * 256 + t;
        int c8 = u & 31, px = u >> 5;
        short8 hv, lv;
#pragma unroll
        for (int j = 0; j < 8; ++j) {
            float f = tile[px * 321 + c8 * 10 + j];
            ushort hb = f2bf(f);
            hv[j] = (short)hb;
            lv[j] = (short)f2bf(f - bf2f(hb));
        }
        size_t addr = ((size_t)b * HWSZ + h * WW + w0 + px) * CHN + c8 * 8;
        *(short8*)(xh + addr) = hv;
        *(short8*)(xl + addr) = lv;
    }
}

// ===========================================================================
// prep_w: w1 -> Bsw (conv B-frags for 32x32x16 MFMA, hi/lo),
//         w2 -> w2sw (head B-frags for 16x16x32, 96-oc pad, unchanged).
// Conv frag (NEW, 32x32): per (tap,kt): fgrp = w*4 + n*2 + ks in [0,16):
//   oc = w*64 + n*32 + (lane&31), ic = kt*32 + ks*16 + (lane>>5)*8 + j
//   Bsw[(tap*8+kt)*16384 + spl*8192 + fgrp*512 + lane*8 + j]
// ===========================================================================
__global__ __launch_bounds__(256) void prep_w(
    const float* __restrict__ w1, const float* __restrict__ w2,
    ushort* __restrict__ Bsw, ushort* __restrict__ w2sw)
{
    int i = blockIdx.x * 256 + threadIdx.x;     // 312*256 = 79872
    if (i < 73728) {                            // 9*8*16*64
        int tap  = i >> 13;
        int rem  = i & 8191;
        int kt   = rem >> 10;
        int rem2 = rem & 1023;
        int fgrp = rem2 >> 6;
        int lane = rem2 & 63;
        int wv   = fgrp >> 2;
        int n    = (fgrp >> 1) & 1;
        int ks   = fgrp & 1;
        int oc   = wv * 64 + n * 32 + (lane & 31);
        int ic0  = kt * 32 + ks * 16 + (lane >> 5) * 8;
        size_t base = (size_t)(tap * 8 + kt) * 16384 + (size_t)fgrp * 512 + lane * 8;
#pragma unroll
        for (int j = 0; j < 8; ++j) {
            float w  = w1[(size_t)oc * 2304 + (ic0 + j) * 9 + tap];
            ushort hb = f2bf(w);
            Bsw[base + j]        = hb;
            Bsw[base + 8192 + j] = f2bf(w - bf2f(hb));
        }
    } else {
        int j2 = i - 73728;                     // < 6144 = 8*2*6*64
        int kt   = j2 / 768;
        int rem  = j2 - kt * 768;
        int spl  = rem / 384;
        int rem2 = rem - spl * 384;
        int ntg  = rem2 >> 6;
        int lane = rem2 & 63;
        int oc   = ntg * 16 + (lane & 15);
        int ic0  = kt * 32 + (lane >> 4) * 8;
        size_t base = (size_t)(kt * 12 + spl * 6 + ntg) * 512 + lane * 8;
#pragma unroll
        for (int j = 0; j < 8; ++j) {
            float w = (oc < NCLS) ? w2[(size_t)oc * CHN + ic0 + j] : 0.f;
            ushort hb = f2bf(w);
            w2sw[base + j] = spl ? f2bf(w - bf2f(hb)) : hb;
        }
    }
}

// ===========================================================================
// conv3_pipe v4: proven R3 pipeline (3-slot buffer, 2-ahead stage, counted
// vmcnt + raw barrier, unchanged LDS layout & swizzle & gl16 staging), but
// the inner product now uses v_mfma_f32_32x32x16_bf16: ~20% more FLOP/cyc
// on the matrix pipe (m119 vs m06) and half the MFMA instruction count.
// Per wave: 4 m-tiles (32px) x 2 n-tiles (32oc), acc = f32x16[4][2] (128 reg).
// A-frag: row = lane&31, k-group = lane>>5 (16B b128 reads; the existing
// chunk swizzle stays perfectly bank-balanced: (4(r&1) + (c^((r>>1)&3)))
// hits each 4-bank group exactly 8x per inst = the b128 floor).
// ===========================================================================
__global__ __launch_bounds__(256, 2) void conv3_pipe(
    const ushort* __restrict__ xh, const ushort* __restrict__ xl,
    const ushort* __restrict__ Bsw, const float* __restrict__ b1,
    float* __restrict__ y)
{
    __shared__ ushort A[3][2][132 * 32];   // [slot=kh][hi/lo][pxs*32 + ch], 50688 B

    const int blk  = blockIdx.x;         // 1024 = 8*128
    const int b    = blk & 7;            // XCD-contiguous: each XCD owns one image
    const int h    = blk >> 3;
    const int t    = threadIdx.x;
    const int lane = t & 63;
    const int w    = t >> 6;             // wave: oc base = w*64
    const int la   = lane & 31;
    const int g    = lane >> 5;

    // per-thread staging constants: 1024 16B units/phase = 128px x 4chunk x 2arr
    int colb[4], basew[4];
#pragma unroll
    for (int r = 0; r < 4; ++r) {
        int e   = (r * 256 + t) & 511;
        int pxs = (e >> 2) + 1;
        int qq  = e & 3;
        int qs  = qq ^ ((pxs >> 1) & 3);          // pre-swizzled source chunk
        colb[r]  = (pxs - 1) * CHN + qs * 8;
        basew[r] = ((((r * 256 + (t & 192)) & 511) >> 2) + 1) * 32;  // wave base
    }

    // A-frag byte offsets (plane-relative): addr = plane + abks[kw][ks] + m*2048
    // pxs = m*32 + la + kw; swizzle bits (pxs>>1)&3 are m-independent.
    int abks[3][2];
#pragma unroll
    for (int kw = 0; kw < 3; ++kw) {
        int la2 = la + kw;
        int sw  = (la2 >> 1) & 3;
#pragma unroll
        for (int ks = 0; ks < 2; ++ks)
            abks[kw][ks] = la2 * 64 + (((((ks << 1) | g)) ^ sw) << 4);
    }

    const short8 zz = {0, 0, 0, 0, 0, 0, 0, 0};
    f32x16 acc[4][2];
#pragma unroll
    for (int i = 0; i < 4; ++i)
#pragma unroll
        for (int j = 0; j < 2; ++j)
#pragma unroll
            for (int r = 0; r < 16; ++r) acc[i][j][r] = 0.f;

    // one-time halo pre-zero: pxs in {0,129,130,131}, all slots/arrays/chunks
    if (t < 96) {
        int sl = t >> 5, rr = t & 31, arr = rr >> 4, pp = (rr >> 2) & 3, qq = rr & 3;
        int pxs = pp ? 128 + pp : 0;
        *(short8*)&A[sl][arr][pxs * 32 + qq * 8] = zz;
    }
    // boundary rows: whole slot is zero for every kt -> zero once, never stage
    if (h == 0 || h == 127) {
        const int sl = (h == 0) ? 0 : 2;
        for (int u = t; u < 1056; u += 256) {     // 2 arrays * 528 16B-units
            int arr = u >= 528; int v = arr ? u - 528 : u;
            *(short8*)&A[sl][arr][v * 8] = zz;
        }
    }

    auto stage = [&](int sn) {
        int kt1 = sn / 3;
        int kh1 = sn - kt1 * 3;                   // also the dest slot
        int gh  = h - 1 + kh1;
        if ((unsigned)gh < (unsigned)HH) {
            size_t rowb = ((size_t)(b * HH + gh) * WW) * CHN + kt1 * 32;
#pragma unroll
            for (int r = 0; r < 4; ++r) {
                const ushort* gp = (r < 2 ? xh : xl) + rowb + colb[r];
                gl16(gp, &A[kh1][r >> 1][basew[r]]);
            }
        }
    };

    stage(0);
    stage(1);

#pragma unroll 1
    for (int s = 0; s < 24; ++s) {
        const int kt = s / 3;
        const int kh = s - kt * 3;                // current slot
        // entry sync: stage(s) must have landed for all waves; leave
        // stage(s+1)'s loads (4, or 0 if skipped boundary row) in flight.
        {
            const int kh1n = (s + 1) % 3;
            const bool nx4 = (s < 23) &&
                !((h == 0 && kh1n == 0) || (h == 127 && kh1n == 2));
            if (nx4) asm volatile("s_waitcnt vmcnt(4) lgkmcnt(0)" ::: "memory");
            else     asm volatile("s_waitcnt vmcnt(0) lgkmcnt(0)" ::: "memory");
            __builtin_amdgcn_s_barrier();
            __builtin_amdgcn_sched_barrier(0);
        }
#pragma unroll
        for (int kw = 0; kw < 3; ++kw) {
            const int tap = kh * 3 + kw;
            const char* bkh = (const char*)Bsw +
                ((size_t)(tap * 8 + kt) << 15) + (w << 12) + (lane << 4);
            const char* bkl = bkh + 16384;
            short8 bh[2][2], bl[2][2];            // [n][ks]
#pragma unroll
            for (int n = 0; n < 2; ++n)
#pragma unroll
                for (int ks = 0; ks < 2; ++ks) {
                    bh[n][ks] = *(const short8*)(bkh + (n * 2 + ks) * 1024);
                    bl[n][ks] = *(const short8*)(bkl + (n * 2 + ks) * 1024);
                }
            if (kw == 0 && s < 22) stage(s + 2);
            const char* pah = (const char*)&A[kh][0][0];
            const char* pal = (const char*)&A[kh][1][0];
#pragma unroll
            for (int ks = 0; ks < 2; ++ks) {
                short8 ah[4], al[4];
#pragma unroll
                for (int m = 0; m < 4; ++m) {
                    ah[m] = *(const short8*)(pah + abks[kw][ks] + m * 2048);
                    al[m] = *(const short8*)(pal + abks[kw][ks] + m * 2048);
                }
                __builtin_amdgcn_s_setprio(1);
#pragma unroll
                for (int n = 0; n < 2; ++n)
#pragma unroll
                    for (int m = 0; m < 4; ++m)
                        acc[m][n] = __builtin_amdgcn_mfma_f32_32x32x16_bf16(
                            ah[m], bh[n][ks], acc[m][n], 0, 0, 0);
#pragma unroll
                for (int n = 0; n < 2; ++n)
#pragma unroll
                    for (int m = 0; m < 4; ++m)
                        acc[m][n] = __builtin_amdgcn_mfma_f32_32x32x16_bf16(
                            ah[m], bl[n][ks], acc[m][n], 0, 0, 0);
#pragma unroll
                for (int n = 0; n < 2; ++n)
#pragma unroll
                    for (int m = 0; m < 4; ++m)
                        acc[m][n] = __builtin_amdgcn_mfma_f32_32x32x16_bf16(
                            al[m], bh[n][ks], acc[m][n], 0, 0, 0);
                __builtin_amdgcn_s_setprio(0);
            }
        }
    }

    // epilogue: oc = w*64 + n*32 + la; px = m*32 + (reg&3) + 8*(reg>>2) + 4*g
    const size_t rowbase = (size_t)b * HWSZ + h * WW;
#pragma unroll
    for (int n = 0; n < 2; ++n) {
        const int oc = w * 64 + n * 32 + la;
        const float bias = b1[oc];
#pragma unroll
        for (int m = 0; m < 4; ++m) {
#pragma unroll
            for (int reg = 0; reg < 16; ++reg) {
                const int px = m * 32 + (reg & 3) + 8 * (reg >> 2) + 4 * g;
                float v = acc[m][n][reg] + bias;
                y[(rowbase + px) * CHN + oc] = v > 0.f ? v : 0.f;
            }
        }
    }
}

// ===========================================================================
// head_mfma v2: 1x1 conv (256->81, pad 96) via MFMA, on-the-fly bf16 split,
// 4-kt register prefetch window (statically indexed). Numerics as R1.
// ===========================================================================
__global__ __launch_bounds__(256) void head_mfma(
    const float* __restrict__ y, const ushort* __restrict__ w2sw,
    const float* __restrict__ b2, float* __restrict__ logits_out,
    int* __restrict__ cls_map, float* __restrict__ prob_map)
{
    __shared__ float ls[128][97];        // [px][oc], pad 97 (conflict-free)
    const int blk = blockIdx.x;          // 1024
    const int b = blk >> 7, h = blk & 127;
    const int t = threadIdx.x, lane = t & 63, wm = t >> 6;
    const int l15 = lane & 15, q = lane >> 4;

    f32x4 acc[2][6];
#pragma unroll
    for (int i = 0; i < 2; ++i)
#pragma unroll
        for (int j = 0; j < 6; ++j) { f32x4 z = {0.f, 0.f, 0.f, 0.f}; acc[i][j] = z; }

    const size_t rowbase = (size_t)b * HWSZ + h * WW;
    const float* yb0 = y + (rowbase + wm * 32 + l15) * CHN + q * 8;
    const float* yb1 = yb0 + 16 * CHN;

    float4 fa[2][4], fb[2][4];           // 4-kt rolling window, static indexing
#pragma unroll
    for (int k = 0; k < 4; ++k) {
        fa[0][k] = *(const float4*)(yb0 + k * 32);
        fb[0][k] = *(const float4*)(yb0 + k * 32 + 4);
        fa[1][k] = *(const float4*)(yb1 + k * 32);
        fb[1][k] = *(const float4*)(yb1 + k * 32 + 4);
    }

#pragma unroll
    for (int kt = 0; kt < 8; ++kt) {
        const int sl = kt & 3;
        short8 ah[2], al[2];
#pragma unroll
        for (int mt = 0; mt < 2; ++mt) {
            float4 f0 = fa[mt][sl];
            float4 f1 = fb[mt][sl];
            float fv[8] = {f0.x, f0.y, f0.z, f0.w, f1.x, f1.y, f1.z, f1.w};
#pragma unroll
            for (int j = 0; j < 8; ++j) {
                ushort hb = f2bf(fv[j]);
                ah[mt][j] = (short)hb;
                al[mt][j] = (short)f2bf(fv[j] - bf2f(hb));
            }
        }
        if (kt < 4) {                    // refill slot for kt+4
            fa[0][sl] = *(const float4*)(yb0 + (kt + 4) * 32);
            fb[0][sl] = *(const float4*)(yb0 + (kt + 4) * 32 + 4);
            fa[1][sl] = *(const float4*)(yb1 + (kt + 4) * 32);
            fb[1][sl] = *(const float4*)(yb1 + (kt + 4) * 32 + 4);
        }
        const ushort* bk = w2sw + (size_t)kt * 12 * 512 + lane * 8;
#pragma unroll
        for (int nt = 0; nt < 6; ++nt) {
            short8 bh = *(const short8*)(bk + nt * 512);
            short8 bl = *(const short8*)(bk + (6 + nt) * 512);
#pragma unroll
            for (int mt = 0; mt < 2; ++mt) {
                acc[mt][nt] = __builtin_amdgcn_mfma_f32_16x16x32_bf16(ah[mt], bh, acc[mt][nt], 0, 0, 0);
                acc[mt][nt] = __builtin_amdgcn_mfma_f32_16x16x32_bf16(ah[mt], bl, acc[mt][nt], 0, 0, 0);
                acc[mt][nt] = __builtin_amdgcn_mfma_f32_16x16x32_bf16(al[mt], bh, acc[mt][nt], 0, 0, 0);
            }
        }
    }

    // bias + stash logits to LDS
#pragma unroll
    for (int nt = 0; nt < 6; ++nt) {
        const int oc = nt * 16 + l15;
        const float bias = (oc < NCLS) ? b2[oc] : 0.f;
#pragma unroll
        for (int mt = 0; mt < 2; ++mt) {
#pragma unroll
            for (int r = 0; r < 4; ++r) {
                const int px = wm * 32 + mt * 16 + q * 4 + r;
                ls[px][oc] = acc[mt][nt][r] + bias;
            }
        }
    }
    __syncthreads();

    // logits out (NCHW), coalesced
    for (int i = t; i < NCLS * 128; i += 256) {
        int c = i >> 7, px = i & 127;
        logits_out[((size_t)b * NCLS + c) * HWSZ + h * WW + px] = ls[px][c];
    }

    // softmax + first-occurrence foreground argmax
    if (t < 128) {
        const int px = t;
        float m = -1e30f;
#pragma unroll
        for (int c = 0; c < NCLS; ++c) m = fmaxf(m, ls[px][c]);
        float s = 0.f;
        for (int c = 0; c < NCLS; ++c) s += expf(ls[px][c] - m);
        float best = -1e30f; int bc = 0;
        for (int c = 0; c < NFG; ++c) {
            float v = ls[px][c];
            if (v > best) { best = v; bc = c; }   // strict > keeps first index
        }
        cls_map[rowbase + px]  = bc;
        prob_map[rowbase + px] = expf(best - m) / s;
    }
}

// ===========================================================================
// locmax (proven)
// ===========================================================================
__global__ __launch_bounds__(256) void locmax_kernel(
    const int* __restrict__ cls_map, const float* __restrict__ prob_map,
    float* __restrict__ score)
{
    int i = blockIdx.x * 256 + threadIdx.x;
    int b = i >> 14;
    int p = i & (HWSZ - 1);
    int h = p >> 7, w = p & 127;
    int mycls = cls_map[i];
    float myp = prob_map[i];
    bool lm = (myp >= EPSV);
#pragma unroll
    for (int dh = -1; dh <= 1; ++dh)
#pragma unroll
        for (int dw = -1; dw <= 1; ++dw) {
            if (dh == 0 && dw == 0) continue;
            int nh = h + dh, nw = w + dw;
            if ((unsigned)nh < HH && (unsigned)nw < WW) {
                int ni = b * HWSZ + nh * WW + nw;
                if (cls_map[ni] == mycls && myp < prob_map[ni]) lm = false;
            }
        }
    score[i] = myp + (lm ? 1.f : 0.f);
}

// ===========================================================================
// topk: 4-level byte-histogram radix select + rank scatter.
// jax.lax.top_k semantics: value desc, tie -> lower index (u64 (key<<32)|~p).
// Bin selection via parallel suffix scan (proven R4).
// ===========================================================================
__global__ __launch_bounds__(1024) void topk_kernel(
    const float* __restrict__ score, int* __restrict__ idx_out)
{
    __shared__ unsigned int hist[256];
    __shared__ unsigned int suf[256];
    __shared__ unsigned long long cand[2048];   // [0..127]: >K, [128..]: ==K
    __shared__ unsigned int sprefix, sneed, scntA, scntB;
    const int b = blockIdx.x;
    const int t = threadIdx.x;
    const float* sc = score + b * HWSZ;

    unsigned keys[16];
#pragma unroll
    for (int i = 0; i < 16; ++i)
        keys[i] = __float_as_uint(sc[t + (i << 10)]);

    if (t == 0) { sneed = KTOP; sprefix = 0; scntA = 0; scntB = 0; }

    for (int lvl = 0; lvl < 4; ++lvl) {
        const int shift = 24 - 8 * lvl;
        if (t < 256) hist[t] = 0;
        __syncthreads();
        const unsigned pref = sprefix;
#pragma unroll
        for (int i = 0; i < 16; ++i) {
            unsigned k = keys[i];
            bool match = (lvl == 0) || ((k >> (shift + 8)) == pref);
            if (match) atomicAdd(&hist[(k >> shift) & 255u], 1u);
        }
        __syncthreads();
        // parallel suffix scan: suf[j] = sum_{k>=j} hist[k]
        if (t < 256) suf[t] = hist[t];
        __syncthreads();
#pragma unroll
        for (int st = 1; st < 256; st <<= 1) {
            unsigned v = 0;
            if (t < 256 && t + st < 256) v = suf[t + st];
            __syncthreads();
            if (t < 256) suf[t] += v;
            __syncthreads();
        }
        const unsigned needv = sneed;
        __syncthreads();
        if (t < 256) {
            unsigned sj  = suf[t];
            unsigned sj1 = (t == 255) ? 0u : suf[t + 1];
            if (sj >= needv && sj1 < needv) {     // unique winner
                sprefix = (pref << 8) | (unsigned)t;
                sneed   = needv - sj1;
            }
        }
        __syncthreads();
    }

    const unsigned K = sprefix;
#pragma unroll
    for (int i = 0; i < 16; ++i) {
        unsigned k = keys[i];
        int p = t + (i << 10);
        if (k > K) {
            unsigned pos = atomicAdd(&scntA, 1u);   // <= 99 guaranteed
            cand[pos] = ((unsigned long long)k << 32) | (unsigned)(~p);
        } else if (k == K) {
            unsigned pos = atomicAdd(&scntB, 1u);
            if (pos < 1920u)
                cand[128 + pos] = ((unsigned long long)k << 32) | (unsigned)(~p);
        }
    }
    __syncthreads();
    const int cA = (int)scntA;
    const int cB = (int)(scntB < 1920u ? scntB : 1920u);
    const int Ctot = cA + cB;
    for (int ti = t; ti < Ctot; ti += 1024) {
        unsigned long long my = cand[ti < cA ? ti : 128 + (ti - cA)];
        int rank = 0;
        for (int j = 0; j < Ctot; ++j) {
            unsigned long long o = cand[j < cA ? j : 128 + (j - cA)];
            rank += (o > my) ? 1 : 0;
        }
        if (rank < KTOP)
            idx_out[b * KTOP + rank] =
                (int)(~(unsigned)(my & 0xFFFFFFFFull)) & (HWSZ - 1);
    }
}

// ===========================================================================
// gather v2 (proven R4): one block per (b, c) -> coalesced writes.
// ===========================================================================
__global__ __launch_bounds__(128) void gather_kernel(
    const float* __restrict__ x, const float* __restrict__ pos,
    const int* __restrict__ idx, float* __restrict__ out0,
    float* __restrict__ out1)
{
    int blk = blockIdx.x;                // 2048 = 8*256
    int b = blk >> 8, c = blk & 255;
    int j = threadIdx.x;
    if (j < KTOP) {
        int pix = idx[b * KTOP + j];
        out0[((size_t)b * CHN + c) * KTOP + j] = x[((size_t)b * CHN + c) * HWSZ + pix];
        out1[((size_t)b * CHN + c) * KTOP + j] = pos[(size_t)c * HWSZ + pix];
    }
}

extern "C" void kernel_launch(void* const* d_in, const int* in_sizes, int n_in,
                              void* d_out, int out_size, void* d_ws, size_t ws_size,
                              hipStream_t stream) {
    (void)in_sizes; (void)n_in; (void)out_size; (void)ws_size;
    const float* x   = (const float*)d_in[0];
    const float* pos = (const float*)d_in[1];
    const float* w1  = (const float*)d_in[2];
    const float* b1  = (const float*)d_in[3];
    const float* w2  = (const float*)d_in[4];
    const float* b2  = (const float*)d_in[5];

    float* out0   = (float*)d_out;                    // [8,256,100]
    float* out1   = out0 + BATCH * CHN * KTOP;        // [8,256,100]
    float* logits = out1 + BATCH * CHN * KTOP;        // [8,81,128,128]

    char* ws = (char*)d_ws;
    const size_t NPX = (size_t)BATCH * HWSZ;          // 131072

    size_t off = 0;
    int*    cls_map  = (int*)(ws + off);    off += NPX * 4;
    float*  prob_map = (float*)(ws + off);  off += NPX * 4;
    float*  score    = (float*)(ws + off);  off += NPX * 4;
    int*    idx      = (int*)(ws + off);    off += 4096;
    ushort* w2sw     = (ushort*)(ws + off); off += (size_t)8 * 12 * 512 * 2;
    ushort* Bsw      = (ushort*)(ws + off); off += (size_t)9 * 8 * 16384 * 2;
    ushort* xh       = (ushort*)(ws + off); off += NPX * CHN * 2;
    ushort* xl       = (ushort*)(ws + off); off += NPX * CHN * 2;
    float*  y        = (float*)(ws + off);  off += NPX * CHN * 4;

    prep_x<<<4096, 256, 0, stream>>>(x, xh, xl);
    prep_w<<<312, 256, 0, stream>>>(w1, w2, Bsw, w2sw);
    conv3_pipe<<<1024, 256, 0, stream>>>(xh, xl, Bsw, b1, y);
    head_mfma<<<1024, 256, 0, stream>>>(y, w2sw, b2, logits, cls_map, prob_map);
    locmax_kernel<<<(int)(NPX / 256), 256, 0, stream>>>(cls_map, prob_map, score);
    topk_kernel<<<BATCH, 1024, 0, stream>>>(score, idx);
    gather_kernel<<<BATCH * CHN, 128, 0, stream>>>(x, pos, idx, out0, out1);
}

// Round 6
// 689.367 us; speedup vs baseline: 1.0244x; 1.0244x over previous
//
#include <hip/hip_runtime.h>
#include <cmath>

#define BATCH 8
#define CHN 256
#define HH 128
#define WW 128
#define HWSZ (HH*WW)
#define NCLS 81
#define NFG 80
#define KTOP 100
#define EPSV 1e-6f

typedef __attribute__((ext_vector_type(8))) short short8;
typedef __attribute__((ext_vector_type(4))) float f32x4;

__device__ __forceinline__ ushort f2bf(float f) {
    unsigned u = __float_as_uint(f);
    return (ushort)((u + 0x7FFFu + ((u >> 16) & 1u)) >> 16);
}
__device__ __forceinline__ float bf2f(ushort h) {
    return __uint_as_float(((unsigned)h) << 16);
}

// async global->LDS, 16B per lane; LDS dest is wave-uniform base + lane*16
__device__ __forceinline__ void gl16(const void* g, void* l) {
    __builtin_amdgcn_global_load_lds(
        (const __attribute__((address_space(1))) void*)g,
        (__attribute__((address_space(3))) void*)l, 16, 0, 0);
}

// ===========================================================================
// prep_x (proven R4): x NCHW fp32 -> xh/xl NHWC bf16 (hi + residual-lo).
// ===========================================================================
__global__ __launch_bounds__(256) void prep_x(
    const float* __restrict__ x, ushort* __restrict__ xh, ushort* __restrict__ xl)
{
    __shared__ float tile[32 * 321];       // 41088 B
    const int blk = blockIdx.x;            // 4096 = 8*128*4
    const int q4 = blk & 3, h = (blk >> 2) & 127, b = blk >> 9;
    const int w0 = q4 << 5;
    const int t = threadIdx.x;
    const int px1 = t & 31, cq = t >> 5;

    const float* xb = x + ((size_t)b * CHN) * HWSZ + h * WW + w0;
#pragma unroll 4
    for (int i = 0; i < 32; ++i) {
        tile[px1 * 321 + i * 10 + cq] = xb[(size_t)(i * 8 + cq) * HWSZ + px1];
    }
    __syncthreads();
    for (int i = 0; i < 4; ++i) {
        int u = i * 256 + t;
        int c8 = u & 31, px = u >> 5;
        short8 hv, lv;
#pragma unroll
        for (int j = 0; j < 8; ++j) {
            float f = tile[px * 321 + c8 * 10 + j];
            ushort hb = f2bf(f);
            hv[j] = (short)hb;
            lv[j] = (short)f2bf(f - bf2f(hb));
        }
        size_t addr = ((size_t)b * HWSZ + h * WW + w0 + px) * CHN + c8 * 8;
        *(short8*)(xh + addr) = hv;
        *(short8*)(xl + addr) = lv;
    }
}

// ===========================================================================
// prep_w (proven R4): w1 -> Bsw (16x16 conv B-frags, hi/lo), w2 -> w2sw.
// Bsw[(tap*8+kt)*16384 + spl*8192 + ntg*512 + lane*8 + j]
// ===========================================================================
__global__ __launch_bounds__(256) void prep_w(
    const float* __restrict__ w1, const float* __restrict__ w2,
    ushort* __restrict__ Bsw, ushort* __restrict__ w2sw)
{
    int i = blockIdx.x * 256 + threadIdx.x;     // 312*256 = 79872
    if (i < 73728) {                            // 9*8*16*64
        int tap  = i >> 13;
        int rem  = i & 8191;
        int kt   = rem >> 10;
        int rem2 = rem & 1023;
        int ntg  = rem2 >> 6;
        int lane = rem2 & 63;
        int oc   = ntg * 16 + (lane & 15);
        int ic0  = kt * 32 + (lane >> 4) * 8;
        size_t base = (size_t)(tap * 8 + kt) * 16384 + (size_t)ntg * 512 + lane * 8;
#pragma unroll
        for (int j = 0; j < 8; ++j) {
            float w  = w1[(size_t)oc * 2304 + (ic0 + j) * 9 + tap];
            ushort hb = f2bf(w);
            Bsw[base + j]        = hb;
            Bsw[base + 8192 + j] = f2bf(w - bf2f(hb));
        }
    } else {
        int j2 = i - 73728;                     // < 6144 = 8*2*6*64
        int kt   = j2 / 768;
        int rem  = j2 - kt * 768;
        int spl  = rem / 384;
        int rem2 = rem - spl * 384;
        int ntg  = rem2 >> 6;
        int lane = rem2 & 63;
        int oc   = ntg * 16 + (lane & 15);
        int ic0  = kt * 32 + (lane >> 4) * 8;
        size_t base = (size_t)(kt * 12 + spl * 6 + ntg) * 512 + lane * 8;
#pragma unroll
        for (int j = 0; j < 8; ++j) {
            float w = (oc < NCLS) ? w2[(size_t)oc * CHN + ic0 + j] : 0.f;
            ushort hb = f2bf(w);
            w2sw[base + j] = spl ? f2bf(w - bf2f(hb)) : hb;
        }
    }
}

// ===========================================================================
// conv3_occ: occupancy rebuild of the proven R4 pipeline. Block = 64px x
// 256oc (grid 2048: 2 width-segments/row), wave = 64px x 64oc -> acc[4][4]
// = 64 acc regs; __launch_bounds__(256,3) -> 3 blocks/CU (12 waves/CU, was
// 8). Same 16x16 MFMA, same chunk swizzle (0-conflict proven), same 3-slot /
// 2-ahead / counted-vmcnt structure (now vmcnt(3): 2 main + 1 halo gl16 per
// wave per stage). One real halo px staged per phase; constant-zero halo
// pre-zeroed once. LDS 25.5 KB/block.
// ===========================================================================
__global__ __launch_bounds__(256, 3) void conv3_occ(
    const ushort* __restrict__ xh, const ushort* __restrict__ xl,
    const ushort* __restrict__ Bsw, const float* __restrict__ b1,
    float* __restrict__ y)
{
    __shared__ ushort A[3][2][68 * 32];   // [slot=kh][hi/lo][row*32 + ch], 26112 B

    const int blk  = blockIdx.x;          // 2048 = (wseg 2)*(h 128)*(b 8)
    const int b    = blk & 7;             // XCD-contiguous: image per XCD
    const int h    = (blk >> 3) & 127;
    const int ws2  = blk >> 10;           // width segment
    const int w0   = ws2 << 6;            // px base (0 or 64)
    const int t    = threadIdx.x;
    const int lane = t & 63;
    const int wv   = t >> 6;              // wave: oc base = wv*64
    const int l15  = lane & 15;
    const int q    = lane >> 4;

    // main staging: wave wv stages LDS rows 1+wv*16 .. 16+wv*16 (16px x 4chunk)
    const int mrow = 1 + wv * 16 + (lane >> 2);
    const int mqs  = (lane & 3) ^ ((mrow >> 1) & 3);      // pre-swizzled chunk
    const int mcol = (w0 + wv * 16 + (lane >> 2)) * CHN + mqs * 8;
    const int mdst = (1 + wv * 16) * 32;                  // uniform per wave
    // halo staging: 1 real px (row hrow), 8 units16 spread over 4 waves x 2 lanes
    const int hrow = ws2 ? 0 : 65;
    const int hgw  = w0 - 1 + hrow;                       // 63 or 64
    const int ha   = wv >> 1;                             // plane
    const int hqb  = (wv & 1) * 2;
    const int hcol = hgw * CHN + (hqb + (lane & 1)) * 8;  // qs=qq (sw(hrow)=0)
    const int hdst = hrow * 32 + hqb * 8;                 // uniform per wave

    // A-frag byte bases (unchanged from R4): addr = plane + abase[kw] + m*1024
    int abase[3];
#pragma unroll
    for (int kw = 0; kw < 3; ++kw) {
        int p0 = l15 + kw;
        abase[kw] = p0 * 64 + ((q ^ ((p0 >> 1) & 3)) << 4);
    }

    const short8 zz = {0, 0, 0, 0, 0, 0, 0, 0};
    f32x4 acc[4][4];
#pragma unroll
    for (int i = 0; i < 4; ++i)
#pragma unroll
        for (int j = 0; j < 4; ++j) { f32x4 z = {0.f, 0.f, 0.f, 0.f}; acc[i][j] = z; }

    // one-time zero: the constant-zero halo row (all slots/planes/chunks)
    if (t < 24) {
        int sl = t >> 3, rr = t & 7, a = rr >> 2, qq = rr & 3;
        int zrow = ws2 ? 65 : 0;
        *(short8*)&A[sl][a][zrow * 32 + qq * 8] = zz;
    }
    // boundary rows (gh OOR): whole slot zero once, never staged
    if (h == 0 || h == 127) {
        const int sl = (h == 0) ? 0 : 2;
        for (int u = t; u < 544; u += 256) {   // 2 planes * 68rows * 4chunks
            int a = u >= 272; int v = a ? u - 272 : u;
            *(short8*)&A[sl][a][v * 8] = zz;
        }
    }

    auto stage = [&](int sn) {
        int kt1 = sn / 3;
        int kh1 = sn - kt1 * 3;                   // dest slot
        int gh  = h - 1 + kh1;
        if ((unsigned)gh < (unsigned)HH) {
            size_t rowb = ((size_t)(b * HH + gh) * WW) * CHN + kt1 * 32;
            gl16(xh + rowb + mcol, &A[kh1][0][mdst]);
            gl16(xl + rowb + mcol, &A[kh1][1][mdst]);
            if (lane < 2)                          // 1 inst/wave, 2 lanes active
                gl16((ha ? xl : xh) + rowb + hcol, &A[kh1][ha][hdst]);
        }
    };

    stage(0);
    stage(1);

#pragma unroll 1
    for (int s = 0; s < 24; ++s) {
        const int kt = s / 3;
        const int kh = s - kt * 3;                // current slot
        // entry sync: stage(s) landed; leave stage(s+1)'s 3 loads in flight.
        {
            const int kh1n = (s + 1) % 3;
            const bool nx = (s < 23) &&
                !((h == 0 && kh1n == 0) || (h == 127 && kh1n == 2));
            if (nx) asm volatile("s_waitcnt vmcnt(3) lgkmcnt(0)" ::: "memory");
            else    asm volatile("s_waitcnt vmcnt(0) lgkmcnt(0)" ::: "memory");
            __builtin_amdgcn_s_barrier();
            __builtin_amdgcn_sched_barrier(0);
        }
#pragma unroll
        for (int kw = 0; kw < 3; ++kw) {
            const int tap = kh * 3 + kw;
            const char* bkh = (const char*)Bsw +
                ((size_t)(tap * 8 + kt) << 15) + (wv << 12) + (lane << 4);
            const char* bkl = bkh + 16384;
            short8 bh[4], bl[4];
#pragma unroll
            for (int nt = 0; nt < 4; ++nt) {
                bh[nt] = *(const short8*)(bkh + nt * 1024);
                bl[nt] = *(const short8*)(bkl + nt * 1024);
            }
            if (kw == 0 && s < 22) stage(s + 2);
            const char* pah = (const char*)&A[kh][0][0] + abase[kw];
            const char* pal = pah + 4352;          // plane stride 68*64 B
            short8 ahf[4], alf[4];
#pragma unroll
            for (int mm = 0; mm < 4; ++mm) {
                ahf[mm] = *(const short8*)(pah + mm * 1024);
                alf[mm] = *(const short8*)(pal + mm * 1024);
            }
            __builtin_amdgcn_s_setprio(1);
#pragma unroll
            for (int nt = 0; nt < 4; ++nt)
#pragma unroll
                for (int mm = 0; mm < 4; ++mm)
                    acc[mm][nt] = __builtin_amdgcn_mfma_f32_16x16x32_bf16(
                        ahf[mm], bh[nt], acc[mm][nt], 0, 0, 0);
#pragma unroll
            for (int nt = 0; nt < 4; ++nt)
#pragma unroll
                for (int mm = 0; mm < 4; ++mm)
                    acc[mm][nt] = __builtin_amdgcn_mfma_f32_16x16x32_bf16(
                        ahf[mm], bl[nt], acc[mm][nt], 0, 0, 0);
#pragma unroll
            for (int nt = 0; nt < 4; ++nt)
#pragma unroll
                for (int mm = 0; mm < 4; ++mm)
                    acc[mm][nt] = __builtin_amdgcn_mfma_f32_16x16x32_bf16(
                        alf[mm], bh[nt], acc[mm][nt], 0, 0, 0);
            __builtin_amdgcn_s_setprio(0);
        }
    }

    // epilogue: px = w0 + mt*16 + q*4 + r, oc = wv*64 + nt*16 + l15
    const size_t rowbase = (size_t)b * HWSZ + h * WW + w0;
#pragma unroll
    for (int nt = 0; nt < 4; ++nt) {
        const int oc = wv * 64 + nt * 16 + l15;
        const float bias = b1[oc];
#pragma unroll
        for (int mt = 0; mt < 4; ++mt) {
#pragma unroll
            for (int r = 0; r < 4; ++r) {
                const int px = mt * 16 + q * 4 + r;
                float v = acc[mt][nt][r] + bias;
                y[(rowbase + px) * CHN + oc] = v > 0.f ? v : 0.f;
            }
        }
    }
}

// ===========================================================================
// head_mfma v2 (proven R4): 1x1 conv via MFMA, 4-kt register prefetch.
// ===========================================================================
__global__ __launch_bounds__(256) void head_mfma(
    const float* __restrict__ y, const ushort* __restrict__ w2sw,
    const float* __restrict__ b2, float* __restrict__ logits_out,
    int* __restrict__ cls_map, float* __restrict__ prob_map)
{
    __shared__ float ls[128][97];        // [px][oc], pad 97 (conflict-free)
    const int blk = blockIdx.x;          // 1024
    const int b = blk >> 7, h = blk & 127;
    const int t = threadIdx.x, lane = t & 63, wm = t >> 6;
    const int l15 = lane & 15, q = lane >> 4;

    f32x4 acc[2][6];
#pragma unroll
    for (int i = 0; i < 2; ++i)
#pragma unroll
        for (int j = 0; j < 6; ++j) { f32x4 z = {0.f, 0.f, 0.f, 0.f}; acc[i][j] = z; }

    const size_t rowbase = (size_t)b * HWSZ + h * WW;
    const float* yb0 = y + (rowbase + wm * 32 + l15) * CHN + q * 8;
    const float* yb1 = yb0 + 16 * CHN;

    float4 fa[2][4], fb[2][4];           // 4-kt rolling window, static indexing
#pragma unroll
    for (int k = 0; k < 4; ++k) {
        fa[0][k] = *(const float4*)(yb0 + k * 32);
        fb[0][k] = *(const float4*)(yb0 + k * 32 + 4);
        fa[1][k] = *(const float4*)(yb1 + k * 32);
        fb[1][k] = *(const float4*)(yb1 + k * 32 + 4);
    }

#pragma unroll
    for (int kt = 0; kt < 8; ++kt) {
        const int sl = kt & 3;
        short8 ah[2], al[2];
#pragma unroll
        for (int mt = 0; mt < 2; ++mt) {
            float4 f0 = fa[mt][sl];
            float4 f1 = fb[mt][sl];
            float fv[8] = {f0.x, f0.y, f0.z, f0.w, f1.x, f1.y, f1.z, f1.w};
#pragma unroll
            for (int j = 0; j < 8; ++j) {
                ushort hb = f2bf(fv[j]);
                ah[mt][j] = (short)hb;
                al[mt][j] = (short)f2bf(fv[j] - bf2f(hb));
            }
        }
        if (kt < 4) {                    // refill slot for kt+4
            fa[0][sl] = *(const float4*)(yb0 + (kt + 4) * 32);
            fb[0][sl] = *(const float4*)(yb0 + (kt + 4) * 32 + 4);
            fa[1][sl] = *(const float4*)(yb1 + (kt + 4) * 32);
            fb[1][sl] = *(const float4*)(yb1 + (kt + 4) * 32 + 4);
        }
        const ushort* bk = w2sw + (size_t)kt * 12 * 512 + lane * 8;
#pragma unroll
        for (int nt = 0; nt < 6; ++nt) {
            short8 bh = *(const short8*)(bk + nt * 512);
            short8 bl = *(const short8*)(bk + (6 + nt) * 512);
#pragma unroll
            for (int mt = 0; mt < 2; ++mt) {
                acc[mt][nt] = __builtin_amdgcn_mfma_f32_16x16x32_bf16(ah[mt], bh, acc[mt][nt], 0, 0, 0);
                acc[mt][nt] = __builtin_amdgcn_mfma_f32_16x16x32_bf16(ah[mt], bl, acc[mt][nt], 0, 0, 0);
                acc[mt][nt] = __builtin_amdgcn_mfma_f32_16x16x32_bf16(al[mt], bh, acc[mt][nt], 0, 0, 0);
            }
        }
    }

    // bias + stash logits to LDS
#pragma unroll
    for (int nt = 0; nt < 6; ++nt) {
        const int oc = nt * 16 + l15;
        const float bias = (oc < NCLS) ? b2[oc] : 0.f;
#pragma unroll
        for (int mt = 0; mt < 2; ++mt) {
#pragma unroll
            for (int r = 0; r < 4; ++r) {
                const int px = wm * 32 + mt * 16 + q * 4 + r;
                ls[px][oc] = acc[mt][nt][r] + bias;
            }
        }
    }
    __syncthreads();

    // logits out (NCHW), coalesced
    for (int i = t; i < NCLS * 128; i += 256) {
        int c = i >> 7, px = i & 127;
        logits_out[((size_t)b * NCLS + c) * HWSZ + h * WW + px] = ls[px][c];
    }

    // softmax + first-occurrence foreground argmax
    if (t < 128) {
        const int px = t;
        float m = -1e30f;
#pragma unroll
        for (int c = 0; c < NCLS; ++c) m = fmaxf(m, ls[px][c]);
        float s = 0.f;
        for (int c = 0; c < NCLS; ++c) s += expf(ls[px][c] - m);
        float best = -1e30f; int bc = 0;
        for (int c = 0; c < NFG; ++c) {
            float v = ls[px][c];
            if (v > best) { best = v; bc = c; }   // strict > keeps first index
        }
        cls_map[rowbase + px]  = bc;
        prob_map[rowbase + px] = expf(best - m) / s;
    }
}

// ===========================================================================
// locmax (proven)
// ===========================================================================
__global__ __launch_bounds__(256) void locmax_kernel(
    const int* __restrict__ cls_map, const float* __restrict__ prob_map,
    float* __restrict__ score)
{
    int i = blockIdx.x * 256 + threadIdx.x;
    int b = i >> 14;
    int p = i & (HWSZ - 1);
    int h = p >> 7, w = p & 127;
    int mycls = cls_map[i];
    float myp = prob_map[i];
    bool lm = (myp >= EPSV);
#pragma unroll
    for (int dh = -1; dh <= 1; ++dh)
#pragma unroll
        for (int dw = -1; dw <= 1; ++dw) {
            if (dh == 0 && dw == 0) continue;
            int nh = h + dh, nw = w + dw;
            if ((unsigned)nh < HH && (unsigned)nw < WW) {
                int ni = b * HWSZ + nh * WW + nw;
                if (cls_map[ni] == mycls && myp < prob_map[ni]) lm = false;
            }
        }
    score[i] = myp + (lm ? 1.f : 0.f);
}

// ===========================================================================
// topk (proven R4): radix select + parallel suffix scan + rank scatter.
// ===========================================================================
__global__ __launch_bounds__(1024) void topk_kernel(
    const float* __restrict__ score, int* __restrict__ idx_out)
{
    __shared__ unsigned int hist[256];
    __shared__ unsigned int suf[256];
    __shared__ unsigned long long cand[2048];   // [0..127]: >K, [128..]: ==K
    __shared__ unsigned int sprefix, sneed, scntA, scntB;
    const int b = blockIdx.x;
    const int t = threadIdx.x;
    const float* sc = score + b * HWSZ;

    unsigned keys[16];
#pragma unroll
    for (int i = 0; i < 16; ++i)
        keys[i] = __float_as_uint(sc[t + (i << 10)]);

    if (t == 0) { sneed = KTOP; sprefix = 0; scntA = 0; scntB = 0; }

    for (int lvl = 0; lvl < 4; ++lvl) {
        const int shift = 24 - 8 * lvl;
        if (t < 256) hist[t] = 0;
        __syncthreads();
        const unsigned pref = sprefix;
#pragma unroll
        for (int i = 0; i < 16; ++i) {
            unsigned k = keys[i];
            bool match = (lvl == 0) || ((k >> (shift + 8)) == pref);
            if (match) atomicAdd(&hist[(k >> shift) & 255u], 1u);
        }
        __syncthreads();
        if (t < 256) suf[t] = hist[t];
        __syncthreads();
#pragma unroll
        for (int st = 1; st < 256; st <<= 1) {
            unsigned v = 0;
            if (t < 256 && t + st < 256) v = suf[t + st];
            __syncthreads();
            if (t < 256) suf[t] += v;
            __syncthreads();
        }
        const unsigned needv = sneed;
        __syncthreads();
        if (t < 256) {
            unsigned sj  = suf[t];
            unsigned sj1 = (t == 255) ? 0u : suf[t + 1];
            if (sj >= needv && sj1 < needv) {     // unique winner
                sprefix = (pref << 8) | (unsigned)t;
                sneed   = needv - sj1;
            }
        }
        __syncthreads();
    }

    const unsigned K = sprefix;
#pragma unroll
    for (int i = 0; i < 16; ++i) {
        unsigned k = keys[i];
        int p = t + (i << 10);
        if (k > K) {
            unsigned pos = atomicAdd(&scntA, 1u);   // <= 99 guaranteed
            cand[pos] = ((unsigned long long)k << 32) | (unsigned)(~p);
        } else if (k == K) {
            unsigned pos = atomicAdd(&scntB, 1u);
            if (pos < 1920u)
                cand[128 + pos] = ((unsigned long long)k << 32) | (unsigned)(~p);
        }
    }
    __syncthreads();
    const int cA = (int)scntA;
    const int cB = (int)(scntB < 1920u ? scntB : 1920u);
    const int Ctot = cA + cB;
    for (int ti = t; ti < Ctot; ti += 1024) {
        unsigned long long my = cand[ti < cA ? ti : 128 + (ti - cA)];
        int rank = 0;
        for (int j = 0; j < Ctot; ++j) {
            unsigned long long o = cand[j < cA ? j : 128 + (j - cA)];
            rank += (o > my) ? 1 : 0;
        }
        if (rank < KTOP)
            idx_out[b * KTOP + rank] =
                (int)(~(unsigned)(my & 0xFFFFFFFFull)) & (HWSZ - 1);
    }
}

// ===========================================================================
// gather v2 (proven R4): one block per (b, c) -> coalesced writes.
// ===========================================================================
__global__ __launch_bounds__(128) void gather_kernel(
    const float* __restrict__ x, const float* __restrict__ pos,
    const int* __restrict__ idx, float* __restrict__ out0,
    float* __restrict__ out1)
{
    int blk = blockIdx.x;                // 2048 = 8*256
    int b = blk >> 8, c = blk & 255;
    int j = threadIdx.x;
    if (j < KTOP) {
        int pix = idx[b * KTOP + j];
        out0[((size_t)b * CHN + c) * KTOP + j] = x[((size_t)b * CHN + c) * HWSZ + pix];
        out1[((size_t)b * CHN + c) * KTOP + j] = pos[(size_t)c * HWSZ + pix];
    }
}

extern "C" void kernel_launch(void* const* d_in, const int* in_sizes, int n_in,
                              void* d_out, int out_size, void* d_ws, size_t ws_size,
                              hipStream_t stream) {
    (void)in_sizes; (void)n_in; (void)out_size; (void)ws_size;
    const float* x   = (const float*)d_in[0];
    const float* pos = (const float*)d_in[1];
    const float* w1  = (const float*)d_in[2];
    const float* b1  = (const float*)d_in[3];
    const float* w2  = (const float*)d_in[4];
    const float* b2  = (const float*)d_in[5];

    float* out0   = (float*)d_out;                    // [8,256,100]
    float* out1   = out0 + BATCH * CHN * KTOP;        // [8,256,100]
    float* logits = out1 + BATCH * CHN * KTOP;        // [8,81,128,128]

    char* ws = (char*)d_ws;
    const size_t NPX = (size_t)BATCH * HWSZ;          // 131072

    size_t off = 0;
    int*    cls_map  = (int*)(ws + off);    off += NPX * 4;
    float*  prob_map = (float*)(ws + off);  off += NPX * 4;
    float*  score    = (float*)(ws + off);  off += NPX * 4;
    int*    idx      = (int*)(ws + off);    off += 4096;
    ushort* w2sw     = (ushort*)(ws + off); off += (size_t)8 * 12 * 512 * 2;
    ushort* Bsw      = (ushort*)(ws + off); off += (size_t)9 * 8 * 16384 * 2;
    ushort* xh       = (ushort*)(ws + off); off += NPX * CHN * 2;
    ushort* xl       = (ushort*)(ws + off); off += NPX * CHN * 2;
    float*  y        = (float*)(ws + off);  off += NPX * CHN * 4;

    prep_x<<<4096, 256, 0, stream>>>(x, xh, xl);
    prep_w<<<312, 256, 0, stream>>>(w1, w2, Bsw, w2sw);
    conv3_occ<<<2048, 256, 0, stream>>>(xh, xl, Bsw, b1, y);
    head_mfma<<<1024, 256, 0, stream>>>(y, w2sw, b2, logits, cls_map, prob_map);
    locmax_kernel<<<(int)(NPX / 256), 256, 0, stream>>>(cls_map, prob_map, score);
    topk_kernel<<<BATCH, 1024, 0, stream>>>(score, idx);
    gather_kernel<<<BATCH * CHN, 128, 0, stream>>>(x, pos, idx, out0, out1);
}